// Round 9
// baseline (157.142 us; speedup 1.0000x reference)
//
#include <hip/hip_runtime.h>
#include <hip/hip_bf16.h>
#include <stdint.h>

#define IC 32
#define OC 32
#define HID 32

// Angle binning: per node, PBIN u64 cells of (count << TSH | sum of t*2^20).
// count: 20 bits (>= A=400k). t-sum: 44 bits (A*2^20 < 2^39). Cells live in
// a static device buffer (g_cells) -- no aliasing with out, no d_ws.
#define PBIN 16
#define TSH 44
#define TSCALE 1048576.0f   // 2^20

// Edge piecewise path: W(t) = M_c + t*K_c per linear piece c; fast path
// handles up to PBE realized pieces (LDS budget), remainder -> edge fixup.
#define PBE 12
#define MAXN 65536          // g_cells capacity (nodes); N larger -> fallback

// LDS piece-matrix layout: 64B rows, +64B pad every 16 rows ->
// row r at f16 index (r + (r>>4))*32. 16 consecutive rows (the 16 ocols a
// quad reads) map to bank-quads (l15+const) mod 8 = 2-way aliasing = free.
// Total: (PBE*2*32 + PBE*2*2) rows = 816 * 64B = 52224 B -> 3 blocks/CU.
#define BROWS (PBE * 2 * 32)
#define BF16N ((BROWS + (BROWS >> 4)) * 32)   // 26112 f16 = 52224 B

typedef __attribute__((ext_vector_type(8))) _Float16 half8;
typedef __attribute__((ext_vector_type(4))) float f32x4;
typedef unsigned long long u64;

static __device__ __forceinline__ _Float16 f2h(float f) { return (_Float16)f; }

// ---------------------------------------------------------------------------
// Device-global scratch (module-load allocated; rewritten in-stream).
// ---------------------------------------------------------------------------
__device__ __align__(16) _Float16 g_MK[PBE * 2 * 32 * 32];
__device__ float g_ekn[16];
__device__ float g_akn[16];
__device__ int   g_npc[2];   // [0]=edge pieces, [1]=angle pieces
__device__ __align__(16) u64 g_cells[(size_t)MAXN * PBIN];   // 8 MB

// ---------------------------------------------------------------------------
// L1: setup (knots + edge piece matrices, blocks < 48) fused with zeroing of
// out and the used cell region (all blocks, grid-stride float4).
//   M_c = eb2 + sum_k on(k,c) b1k eW2k,  K_c = sum_k on(k,c) w1k eW2k
// on(k,c) = (w>0) ? (on0||flip) : (on0&&!flip), flip = realized && rank_k < c.
// ---------------------------------------------------------------------------
__global__ __launch_bounds__(512) void setup_zero(
    const float* __restrict__ eW1, const float* __restrict__ eb1,
    const float* __restrict__ eW2, const float* __restrict__ eb2,
    const float* __restrict__ aW1, const float* __restrict__ ab1,
    float* __restrict__ out, int outF4, int cellF4)
{
    __shared__ float ts_s[32];
    __shared__ int   rk_s[32];
    __shared__ int   re_s[32];
    const int tid = threadIdx.x;
    const int bid = blockIdx.x;

    if (bid < 48) {
        if (bid == 0 && tid < 16) { g_ekn[tid] = 1e30f; g_akn[tid] = 1e30f; }
        if (tid < 32) {   // edge-MLP hinge table (shared: matrices need it)
            const int k = tid;
            const float w = eW1[k], b = eb1[k];
            const float ts = -b / w;
            const bool re = (w != 0.f) && (ts > 0.f) && (ts < 1.f);
            int rk = 0;
            for (int k2 = 0; k2 < 32; ++k2) {
                const float w2 = eW1[k2], b2 = eb1[k2];
                const float t2 = -b2 / w2;
                const bool re2 = (w2 != 0.f) && (t2 > 0.f) && (t2 < 1.f);
                rk += (re2 && (t2 < ts || (t2 == ts && k2 < k))) ? 1 : 0;
            }
            ts_s[k] = ts; rk_s[k] = rk; re_s[k] = re ? 1 : 0;
        }
        __syncthreads();

        if (bid == 0) {
            if (tid < 32) {
                if (re_s[tid]) g_ekn[rk_s[tid]] = ts_s[tid];
                if (tid == 0) {
                    int n = 0;
                    for (int k = 0; k < 32; ++k) n += re_s[k];
                    g_npc[0] = n + 1;
                }
            } else if (tid < 64) {   // angle-MLP knots
                const int k = tid - 32;
                const float w = aW1[k], b = ab1[k];
                const float ts = -b / w;
                const bool re = (w != 0.f) && (ts > 0.f) && (ts < 1.f);
                int rk = 0, nre = 0;
                for (int k2 = 0; k2 < 32; ++k2) {
                    const float w2 = aW1[k2], b2 = ab1[k2];
                    const float t2 = -b2 / w2;
                    const bool re2 = (w2 != 0.f) && (t2 > 0.f) && (t2 < 1.f);
                    nre += re2 ? 1 : 0;
                    rk += (re2 && (t2 < ts || (t2 == ts && k2 < k))) ? 1 : 0;
                }
                if (re) g_akn[rk] = ts;
                if (k == 0) g_npc[1] = nre + 1;
            }
        }

        const int gid = bid * 512 + tid;   // piece-matrix entries (48 blocks)
        if (gid < PBE * 2 * 32 * 32) {
            const int i   = gid & 31;
            const int o   = (gid >> 5) & 31;
            const int mat = (gid >> 10) & 1;
            const int cc  = gid >> 11;
            float acc = (mat == 0) ? eb2[i * 32 + o] : 0.f;
            for (int k = 0; k < 32; ++k) {
                const bool flip = re_s[k] && (rk_s[k] < cc);
                const float w = eW1[k], b = eb1[k];
                const bool on0 = b > 0.f;
                const bool on = (w > 0.f) ? (on0 || flip) : (on0 && !flip);
                if (on) acc = fmaf((mat == 0 ? b : w),
                                   eW2[k * 1024 + i * 32 + o], acc);
            }
            g_MK[((cc * 2 + mat) * 32 + o) * 32 + i] = (_Float16)acc;
        }
    }

    // ---- zero out + used cells (all blocks) ----
    const int total = outF4 + cellF4;
    const float4 z4 = make_float4(0.f, 0.f, 0.f, 0.f);
    for (int i = bid * 512 + tid; i < total; i += gridDim.x * 512) {
        if (i < outF4) ((float4*)out)[i] = z4;
        else           ((float4*)g_cells)[i - outF4] = z4;
    }
}

// ---------------------------------------------------------------------------
// L2: bin angles. cc = #realized knots <= t; one u64 atomic per angle.
// cells == nullptr -> use g_cells (fast path); else caller-provided.
// ---------------------------------------------------------------------------
__global__ __launch_bounds__(256) void angle_scatter(
    const float* __restrict__ angles, const int* __restrict__ angle_index,
    u64* __restrict__ cells, int A)
{
    u64* cp = cells ? cells : g_cells;
    float kn[16];
#pragma unroll
    for (int j = 0; j < 16; ++j) kn[j] = g_akn[j];

    int i0 = blockIdx.x * blockDim.x + threadIdx.x;
    int stride = gridDim.x * blockDim.x;
    for (int a = i0; a < A; a += stride) {
        const float t = angles[a];
        const int j = angle_index[A + a];   // center node
        int cc = 0;
#pragma unroll
        for (int jj = 0; jj < 16; ++jj) cc += (t >= kn[jj]) ? 1 : 0;
        if ((unsigned)cc < (unsigned)PBIN) {
            const u64 enc = ((u64)1 << TSH) | (u64)(unsigned)(t * TSCALE);
            atomicAdd(cp + (size_t)j * PBIN + cc, enc);
        }
    }
}

// ---------------------------------------------------------------------------
// Gather body (proven in R6-R8): per wave 16 nodes; lane (l15,q) builds
// g[k] = sum_c n_c*relu(tb_c*w1k+b1k); two mfma_f32_16x16x32_f16 -> 32 ch.
// addmode: atomicAdd into zeroed out (mega path); else overwrite in place.
// ---------------------------------------------------------------------------
static __device__ __forceinline__ void angle_gather_wave(
    const u64* __restrict__ cells, float* __restrict__ out,
    const float* __restrict__ aW1, const float* __restrict__ ab1,
    const float* __restrict__ aW2, const float* __restrict__ ab2,
    int N, int base, int lane, bool addmode)
{
    const int q = lane >> 4, l15 = lane & 15;
    float w1s[8], b1s[8];
    int c0 = 0, c1 = 0;
#pragma unroll
    for (int k = 0; k < HID; ++k) {
        const float w = aW1[k], b = ab1[k];
        const bool pos = w > 0.f;
        const bool f0 = pos ? (b > 0.f) : !(b > 0.f);
        const bool f1 = pos ? ((w + b) > 0.f) : !((w + b) > 0.f);
        c0 += f0 ? 1 : 0;
        c1 += f1 ? 1 : 0;
        if ((k >> 3) == q) { w1s[k & 7] = w; b1s[k & 7] = b; }
    }
    int npc = c1 - c0 + 1;
    if (npc > PBIN) npc = PBIN;

    half8 Bf0, Bf1;
#pragma unroll
    for (int j = 0; j < 8; ++j) {
        Bf0[j] = f2h(aW2[(q * 8 + j) * OC + l15]);
        Bf1[j] = f2h(aW2[(q * 8 + j) * OC + 16 + l15]);
    }
    const float bias0 = ab2[l15];
    const float bias1 = ab2[16 + l15];

    const int jn = base + l15;
    const bool vn = (jn < N);
    const u64* cj = cells + (size_t)(vn ? jn : 0) * PBIN;
    float g[8] = {0.f, 0.f, 0.f, 0.f, 0.f, 0.f, 0.f, 0.f};
    float tot = 0.f;
    for (int cc = 0; cc < npc; ++cc) {
        const u64 v = vn ? cj[cc] : 0;
        if (v) {
            const float n  = (float)(unsigned)(v >> TSH);
            const float ts = (float)(v & (((u64)1 << TSH) - 1)) * (1.f / TSCALE);
            const float tb = ts / n;
#pragma unroll
            for (int k = 0; k < 8; ++k) {
                float h = fmaf(tb, w1s[k], b1s[k]);
                h = h > 0.f ? h : 0.f;
                g[k] = fmaf(n, h, g[k]);
            }
            tot += n;
        }
    }
    half8 a;
#pragma unroll
    for (int k = 0; k < 8; ++k) a[k] = f2h(g[k]);

    f32x4 acc0 = {0.f, 0.f, 0.f, 0.f};
    f32x4 acc1 = {0.f, 0.f, 0.f, 0.f};
    acc0 = __builtin_amdgcn_mfma_f32_16x16x32_f16(a, Bf0, acc0, 0, 0, 0);
    acc1 = __builtin_amdgcn_mfma_f32_16x16x32_f16(a, Bf1, acc1, 0, 0, 0);

#pragma unroll
    for (int r = 0; r < 4; ++r) {
        const int node = base + q * 4 + r;
        const float tr = __shfl(tot, q * 4 + r, 64);
        if (node < N) {
            const float v0 = fmaf(tr, bias0, acc0[r]);
            const float v1 = fmaf(tr, bias1, acc1[r]);
            if (addmode) {
                unsafeAtomicAdd(out + (size_t)node * OC + l15, v0);
                unsafeAtomicAdd(out + (size_t)node * OC + 16 + l15, v1);
            } else {
                out[(size_t)node * OC + l15]      = v0;
                out[(size_t)node * OC + 16 + l15] = v1;
            }
        }
    }
}

// Fallback standalone gather (N > MAXN): cells in out, overwrite mode.
__global__ __launch_bounds__(256) void angle_gather_ow(
    float* __restrict__ out,
    const float* __restrict__ aW1, const float* __restrict__ ab1,
    const float* __restrict__ aW2, const float* __restrict__ ab2, int N)
{
    const int lane = threadIdx.x & 63;
    const int wib  = threadIdx.x >> 6;
    const int base = (blockIdx.x * 4 + wib) * 16;
    if (base >= N) return;
    angle_gather_wave((const u64*)out, out, aW1, ab1, aW2, ab2,
                      N, base, lane, false);
}

// ---------------------------------------------------------------------------
// L3: mega kernel -- all post-scatter work as additive block roles:
//   [0,EB):        edge (piecewise W(t), K=64 MFMA, LDS piece matrices)
//   [EB,EB+GB):    angle gather (atomicAdd)
//   [.., +FA):     angle fixup (cc >= PBIN; uniform-empty unless npc_a > 16)
//   [.., +FE):     edge fixup  (cc >= PBE;  uniform-empty unless npc_e > 12)
// LDS = 52224 B (padded-row layout, see BF16N) -> 3 blocks/CU (was 2 at
// 61952): the R9 experiment discriminating latency-bound vs atomic-rate.
// ---------------------------------------------------------------------------
__global__ __launch_bounds__(512, 4) void mega_kernel(
    const float* __restrict__ x, const int* __restrict__ edge_index,
    const float* __restrict__ edge_attr,
    const float* __restrict__ eW1, const float* __restrict__ eb1,
    const float* __restrict__ eW2, const float* __restrict__ eb2,
    const float* __restrict__ angles, const int* __restrict__ angle_index,
    const float* __restrict__ aW1, const float* __restrict__ ab1,
    const float* __restrict__ aW2, const float* __restrict__ ab2,
    float* __restrict__ out, int E, int A, int N,
    int EB, int GB, int FA, int FE)
{
    // padded rows: row r (of 768) lives at f16 index (r + (r>>4))*32.
    __shared__ __align__(16) _Float16 B[BF16N];
    __shared__ float knl[16];

    const int tid = threadIdx.x;
    const int bid = blockIdx.x;

    if (bid < EB) {
        // ================= edge role (R7 structure, 8 waves) =================
        // stage: chunk idx -> row r = idx>>2, 16B chunk ch = idx&3;
        // dst float4 index = (r + (r>>4))*4 + ch (injective, r monotone).
        for (int idx = tid; idx < BROWS * 4; idx += 512) {
            const int r = idx >> 2, ch = idx & 3;
            ((float4*)B)[(r + (r >> 4)) * 4 + ch] = ((const float4*)g_MK)[idx];
        }
        if (tid < 16) knl[tid] = g_ekn[tid];
        __syncthreads();

        float kn[PBE];
#pragma unroll
        for (int j = 0; j < PBE; ++j) kn[j] = knl[j];
        int npc = g_npc[0];
        if (npc > PBE) npc = PBE;

        const int lane  = tid & 63;
        const int w8    = tid >> 6;
        const int gwave = bid * 8 + w8;
        const int ot    = gwave & 1;
        const int tile0 = gwave >> 1;
        const int tstride = (EB * 8) >> 1;
        const int q     = lane >> 4;
        const int l15   = lane & 15;
        const int ocol  = ot * 16 + l15;
        // lane base: row (cm*32 + ocol) at (r + (r>>4))*32 with r>>4 = cm*2+ot
        // -> index = cm*1088 + (ocol + ot)*32 + q*8; piece stride 2176 f16.
        const _Float16* Bb = B + (ocol + ot) * 32 + q * 8;

        const int numTiles = (E + 15) >> 4;

        for (int tile = tile0; tile < numTiles; tile += 2 * tstride) {
            const int tA = tile;
            const int tB = tile + tstride;
            const bool hasB = (tB < numTiles);

            const int eA  = (tA << 4) + l15;
            const bool va = (eA < E);
            const float ta = va ? edge_attr[eA] : 0.f;
            const int colA = va ? edge_index[E + eA] : 0;

            const int eB  = (tB << 4) + l15;
            const bool vb = hasB && (eB < E);
            const float tb = vb ? edge_attr[eB] : 0.f;
            const int colB = vb ? edge_index[E + eB] : 0;

            const float* xpA = x + (size_t)colA * IC + q * 8;
            const float4 xloA = *(const float4*)(xpA);
            const float4 xhiA = *(const float4*)(xpA + 4);
            const float* xpB = x + (size_t)colB * IC + q * 8;
            const float4 xloB = *(const float4*)(xpB);
            const float4 xhiB = *(const float4*)(xpB + 4);

            int dstsA[4], dstsB[4];
            const int ebaseA = (tA << 4) + q * 4;
            const int ebaseB = (tB << 4) + q * 4;
#pragma unroll
            for (int r = 0; r < 4; ++r) {
                const int erA = ebaseA + r;
                dstsA[r] = (erA < E) ? edge_index[erA] : -1;
                const int erB = ebaseB + r;
                dstsB[r] = (hasB && erB < E) ? edge_index[erB] : -1;
            }

            int ccA = 0, ccB = 0;
#pragma unroll
            for (int j = 0; j < PBE; ++j) {
                ccA += (ta >= kn[j]) ? 1 : 0;
                ccB += (tb >= kn[j]) ? 1 : 0;
            }

            half8 xhA, xhB;
            xhA[0] = f2h(xloA.x); xhA[1] = f2h(xloA.y);
            xhA[2] = f2h(xloA.z); xhA[3] = f2h(xloA.w);
            xhA[4] = f2h(xhiA.x); xhA[5] = f2h(xhiA.y);
            xhA[6] = f2h(xhiA.z); xhA[7] = f2h(xhiA.w);
            xhB[0] = f2h(xloB.x); xhB[1] = f2h(xloB.y);
            xhB[2] = f2h(xloB.z); xhB[3] = f2h(xloB.w);
            xhB[4] = f2h(xhiB.x); xhB[5] = f2h(xhiB.y);
            xhB[6] = f2h(xhiB.z); xhB[7] = f2h(xhiB.w);

            const _Float16 thA = f2h(ta), thB = f2h(tb);
            const half8 tvA = {thA, thA, thA, thA, thA, thA, thA, thA};
            const half8 tvB = {thB, thB, thB, thB, thB, thB, thB, thB};
            const half8 xtA = xhA * tvA;
            const half8 xtB = xhB * tvB;
            const half8 z = {0, 0, 0, 0, 0, 0, 0, 0};

            f32x4 accA = {0.f, 0.f, 0.f, 0.f};
            f32x4 accB = {0.f, 0.f, 0.f, 0.f};
            for (int c = 0; c < npc; ++c) {
                const half8 bM = *(const half8*)(Bb + c * 2176);
                const half8 bK = *(const half8*)(Bb + c * 2176 + 1088);
                const half8 aA1 = (ccA == c) ? xhA : z;
                const half8 aA2 = (ccA == c) ? xtA : z;
                const half8 aB1 = (ccB == c) ? xhB : z;
                const half8 aB2 = (ccB == c) ? xtB : z;
                accA = __builtin_amdgcn_mfma_f32_16x16x32_f16(aA1, bM, accA, 0, 0, 0);
                accB = __builtin_amdgcn_mfma_f32_16x16x32_f16(aB1, bM, accB, 0, 0, 0);
                accA = __builtin_amdgcn_mfma_f32_16x16x32_f16(aA2, bK, accA, 0, 0, 0);
                accB = __builtin_amdgcn_mfma_f32_16x16x32_f16(aB2, bK, accB, 0, 0, 0);
            }

#pragma unroll
            for (int r = 0; r < 4; ++r) {
                if (dstsA[r] >= 0)
                    unsafeAtomicAdd(out + (size_t)dstsA[r] * OC + ocol, accA[r]);
            }
#pragma unroll
            for (int r = 0; r < 4; ++r) {
                if (dstsB[r] >= 0)
                    unsafeAtomicAdd(out + (size_t)dstsB[r] * OC + ocol, accB[r]);
            }
        }
    } else if (bid < EB + GB) {
        // ================= angle gather role (atomicAdd) ====================
        const int lane = tid & 63;
        const int wib  = tid >> 6;
        const int base = ((bid - EB) * 8 + wib) * 16;
        if (base < N)
            angle_gather_wave(g_cells, out, aW1, ab1, aW2, ab2,
                              N, base, lane, true);
    } else if (bid < EB + GB + FA) {
        // ================= angle fixup role (cc >= PBIN) ====================
        if (g_npc[1] <= PBIN) return;
        const float kn15 = g_akn[15];
        float w1[HID], b1[HID];
#pragma unroll
        for (int k = 0; k < HID; ++k) { w1[k] = aW1[k]; b1[k] = ab1[k]; }
        int i0 = (bid - EB - GB) * 512 + tid;
        int stride = FA * 512;
        for (int a = i0; a < A; a += stride) {
            const float t = angles[a];
            if (t < kn15) continue;
            const int j = angle_index[A + a];
            float h[HID];
#pragma unroll
            for (int k = 0; k < HID; ++k) {
                float v = fmaf(t, w1[k], b1[k]);
                h[k] = v > 0.f ? v : 0.f;
            }
            for (int o = 0; o < OC; ++o) {
                float s = ab2[o];
#pragma unroll
                for (int k = 0; k < HID; ++k) s = fmaf(h[k], aW2[k * OC + o], s);
                unsafeAtomicAdd(out + (size_t)j * OC + o, s);
            }
        }
    } else {
        // ================= edge fixup role (cc >= PBE) ======================
        if (g_npc[0] <= PBE) return;
        const float knb = g_ekn[PBE - 1];
        int i0 = (bid - EB - GB - FA) * 512 + tid;
        int stride = FE * 512;
        for (int e = i0; e < E; e += stride) {
            const float t = edge_attr[e];
            if (t < knb) continue;
            const int col = edge_index[E + e];
            const int dst = edge_index[e];
            float h[HID];
#pragma unroll
            for (int k = 0; k < HID; ++k) {
                float v = fmaf(t, eW1[k], eb1[k]);
                h[k] = v > 0.f ? v : 0.f;
            }
            for (int o = 0; o < OC; ++o) {
                float s = 0.f;
                for (int i = 0; i < IC; ++i) {
                    float wio = eb2[i * 32 + o];
#pragma unroll
                    for (int k = 0; k < HID; ++k)
                        wio = fmaf(h[k], eW2[k * 1024 + i * 32 + o], wio);
                    s = fmaf(x[(size_t)col * IC + i], wio, s);
                }
                unsafeAtomicAdd(out + (size_t)dst * OC + o, s);
            }
        }
    }
}

// ---------------------------------------------------------------------------
extern "C" void kernel_launch(void* const* d_in, const int* in_sizes, int n_in,
                              void* d_out, int out_size, void* d_ws, size_t ws_size,
                              hipStream_t stream)
{
    const float* x          = (const float*)d_in[0];
    const int*   edge_index = (const int*)d_in[1];
    const float* edge_attr  = (const float*)d_in[2];
    const int*   angle_index= (const int*)d_in[3];
    const float* angles     = (const float*)d_in[4];
    const float* eW1        = (const float*)d_in[5];
    const float* eb1        = (const float*)d_in[6];
    const float* eW2        = (const float*)d_in[7];
    const float* eb2        = (const float*)d_in[8];
    const float* aW1        = (const float*)d_in[9];
    const float* ab1        = (const float*)d_in[10];
    const float* aW2        = (const float*)d_in[11];
    const float* ab2        = (const float*)d_in[12];
    float* out = (float*)d_out;
    (void)d_ws; (void)ws_size;

    const int E = in_sizes[1] / 2;
    const int A = in_sizes[3] / 3;
    const int N = in_sizes[0] / IC;

    const int outF4 = out_size / 4;   // out_size is float count
    const int sblocks = (A + 255) / 256;

    if (N <= MAXN) {
        // ---- fast path: 3 launches ----
        const int cellF4 = N * 8;     // N*16 u64 = N*8 float4
        int zg = (outF4 + cellF4 + 511) / 512;
        if (zg < 48) zg = 48;
        setup_zero<<<zg, 512, 0, stream>>>(eW1, eb1, eW2, eb2, aW1, ab1,
                                           out, outF4, cellF4);

        angle_scatter<<<sblocks, 256, 0, stream>>>(angles, angle_index,
                                                   nullptr, A);

        const int EB = 512;
        const int GB = (N + 127) / 128;
        const int FA = 64, FE = 64;
        mega_kernel<<<EB + GB + FA + FE, 512, 0, stream>>>(
            x, edge_index, edge_attr, eW1, eb1, eW2, eb2,
            angles, angle_index, aW1, ab1, aW2, ab2,
            out, E, A, N, EB, GB, FA, FE);
    } else {
        // ---- fallback (N > MAXN): cells in out, gather overwrites ----
        int zg = (outF4 + 511) / 512;
        if (zg < 48) zg = 48;
        setup_zero<<<zg, 512, 0, stream>>>(eW1, eb1, eW2, eb2, aW1, ab1,
                                           out, outF4, 0);
        angle_scatter<<<sblocks, 256, 0, stream>>>(angles, angle_index,
                                                   (u64*)out, A);
        angle_gather_ow<<<(N + 63) / 64, 256, 0, stream>>>(out, aW1, ab1,
                                                           aW2, ab2, N);
        const int EB = 512, FA = 64, FE = 64;
        mega_kernel<<<EB + FA + FE, 512, 0, stream>>>(
            x, edge_index, edge_attr, eW1, eb1, eW2, eb2,
            angles, angle_index, aW1, ab1, aW2, ab2,
            out, E, A, N, EB, 0, FA, FE);
    }
}